// Round 10
// baseline (160.542 us; speedup 1.0000x reference)
//
#include <hip/hip_runtime.h>
#include <hip/hip_bf16.h>

// out[M=131072, N=512] = x[M, K=512] @ W^T[N=512, K=512] + bias[N]
// fp32 in/out; bf16 MFMA (fp32 accum).
//
// Kernel 1: repack W fp32 -> bf16 MFMA-fragment layout in d_ws (512 KB)
//   (r8-verified layout: block tk = t*16+kb, t = 16-col tile).
// Kernel 2: GEMM, round-10: 2-TILE IN-BLOCK PIPELINE. Rounds 1-9 all fit a
//   sum-of-phases model (~156us = HBM 64 + B-stream 29 + MFMA 28 + VALU 17 +
//   staging): each block is [read burst][compute, HBM idle][store burst] and
//   co-resident blocks stay phase-aligned, so nothing overlaps. Now each
//   block owns TWO 64-row tiles with two full-K LDS buffers (2x64KB):
//   t1's global loads are issued before t0's compute (HBM read hides under
//   compute), and t0's NT stores issue into the top of t1's compute (store
//   burst hides too). 16 waves (wave tile 64x32, acc=32), single N-pass,
//   barrier-free K-loops (r8-verified swizzle/compute/epilogue).
//   v_cvt_pk packing; NT stores keep L2 for wf.

#define M_TOTAL 131072
#define KDIM 512
#define NDIM 512
#define BM 64
#define NKSTEP 16

typedef __attribute__((ext_vector_type(8))) short bf16x8;
typedef __attribute__((ext_vector_type(4))) float f32x4;
typedef __attribute__((ext_vector_type(4))) float fv4;
typedef __attribute__((ext_vector_type(4))) int iv4;

__device__ __forceinline__ iv4 pack8(fv4 lo, fv4 hi) {
    union { __hip_bfloat162 h[4]; iv4 v; } p;
    p.h[0] = __float22bfloat162_rn(float2{lo[0], lo[1]});
    p.h[1] = __float22bfloat162_rn(float2{lo[2], lo[3]});
    p.h[2] = __float22bfloat162_rn(float2{hi[0], hi[1]});
    p.h[3] = __float22bfloat162_rn(float2{hi[2], hi[3]});
    return p.v;
}

// wf[((t*16+kb)*64 + l)*8 + j] = bf16( W[t*16 + (l&15)][kb*32 + (l>>4)*8 + j] )
__global__ void repack_w_kernel(const float* __restrict__ w,
                                unsigned short* __restrict__ wf) {
    const int gtid = blockIdx.x * 256 + threadIdx.x;  // 0..32767
    const int tk = gtid >> 6;   // t*16 + kb
    const int l  = gtid & 63;
    const int n  = (tk >> 4) * 16 + (l & 15);
    const int k0 = (tk & 15) * 32 + (l >> 4) * 8;
    const fv4* src = reinterpret_cast<const fv4*>(w + n * KDIM + k0);
    *reinterpret_cast<iv4*>(wf + tk * 512 + l * 8) = pack8(src[0], src[1]);
}

__global__ __launch_bounds__(1024, 4) void linear_bf16_kernel(
    const float* __restrict__ x, const unsigned short* __restrict__ wf,
    const float* __restrict__ bias, float* __restrict__ out) {
    // per tile: 64 rows x 512 cols bf16, 16B-chunk swizzled (r5/r8-verified):
    //   ushort idx = row*512 + ((chunk ^ (row&7))<<3) + (col&7), chunk=col>>3
    __shared__ __attribute__((aligned(16))) unsigned short lds_a[2][BM * KDIM];  // 128 KB

    const int tid  = threadIdx.x;
    const int lane = tid & 63;
    const int wc   = tid >> 6;   // 0..15 -> 32-col strip
    const int fr   = lane & 15;
    const int fc   = lane >> 4;  // k-chunk 0..3

    const int rowbase0 = blockIdx.x * 2 * BM;

    // ---- staging coords: thread -> row tid>>4 (0..63), stripe q = tid&15 ----
    const int srow = tid >> 4;
    const int q    = tid & 15;
    const int skey = (srow & 7) << 3;

    fv4 st[8];  // 32 VGPR staging (held in flight across t0 compute for t1)
    auto LOADT = [&](int t) {
        const float* xrow = x + (size_t)(rowbase0 + t * BM + srow) * KDIM;
#pragma unroll
        for (int i = 0; i < 4; ++i) {
            const fv4* src = reinterpret_cast<const fv4*>(xrow + (i * 16 + q) * 8);
            st[2 * i]     = src[0];
            st[2 * i + 1] = src[1];
        }
    };
    auto WRITET = [&](int buf) {
#pragma unroll
        for (int i = 0; i < 4; ++i) {
            const int c = i * 16 + q;  // 16B chunk 0..63
            *reinterpret_cast<iv4*>(&lds_a[buf][srow * 512 + ((c << 3) ^ skey)]) =
                pack8(st[2 * i], st[2 * i + 1]);
        }
    };

    const int akey = (fr & 7) << 3;  // row&7 invariant under +m*16

    f32x4 acc[4][2];
    bf16x8 bfv[2][2];  // B double buffer
    auto LOADB = [&](int buf, int kb) {
#pragma unroll
        for (int n = 0; n < 2; ++n)
            bfv[buf][n] = *reinterpret_cast<const bf16x8*>(
                wf + (size_t)(((wc * 2 + n) * 16 + kb) * 512) + lane * 8);
    };
    auto ZERO = [&]() {
#pragma unroll
        for (int m = 0; m < 4; ++m)
#pragma unroll
            for (int n = 0; n < 2; ++n)
                acc[m][n] = (f32x4){0.f, 0.f, 0.f, 0.f};
    };
    auto KLOOP = [&](int buf) {
        LOADB(0, 0);
#pragma unroll
        for (int kb = 0; kb < NKSTEP; ++kb) {
            if (kb + 1 < NKSTEP) LOADB((kb + 1) & 1, kb + 1);  // L2, 1 ahead
            bf16x8 af[4];
#pragma unroll
            for (int m = 0; m < 4; ++m)
                af[m] = *reinterpret_cast<const bf16x8*>(
                    &lds_a[buf][(m * 16 + fr) * 512 + (((kb * 4 + fc) << 3) ^ akey)]);
#pragma unroll
            for (int n = 0; n < 2; ++n)
#pragma unroll
                for (int m = 0; m < 4; ++m)
                    acc[m][n] = __builtin_amdgcn_mfma_f32_16x16x32_bf16(
                        af[m], bfv[kb & 1][n], acc[m][n], 0, 0, 0);
        }
    };

    float bv[2];
#pragma unroll
    for (int n = 0; n < 2; ++n)
        bv[n] = bias[wc * 32 + n * 16 + fr];

    auto STORE = [&](int t) {
        float* ob = out + (size_t)(rowbase0 + t * BM + fc * 4) * NDIM + wc * 32 + fr;
#pragma unroll
        for (int m = 0; m < 4; ++m)
#pragma unroll
            for (int j = 0; j < 4; ++j) {
                float* orow = ob + (m * 16 + j) * NDIM;
#pragma unroll
                for (int n = 0; n < 2; ++n)
                    __builtin_nontemporal_store(acc[m][n][j] + bv[n], &orow[n * 16]);
            }
    };

    // ---- tile 0 stage ----
    LOADT(0);
    WRITET(0);
    __syncthreads();

    // ---- t1 HBM loads issue now; stay in flight under t0 compute ----
    LOADT(1);

    ZERO();
    KLOOP(0);          // tile-0 compute (barrier-free); t1 reads land meanwhile

    WRITET(1);         // counted vmcnt waits for t1 loads; pack + ds_write
    __syncthreads();

    STORE(0);          // t0 store burst issues into the top of t1 compute
    ZERO();
    KLOOP(1);          // tile-1 compute

    STORE(1);
}

extern "C" void kernel_launch(void* const* d_in, const int* in_sizes, int n_in,
                              void* d_out, int out_size, void* d_ws, size_t ws_size,
                              hipStream_t stream) {
    const float* x    = (const float*)d_in[0];
    const float* w    = (const float*)d_in[1];
    const float* bias = (const float*)d_in[2];
    float* out        = (float*)d_out;
    unsigned short* wf = (unsigned short*)d_ws;  // 512 KB

    hipLaunchKernelGGL(repack_w_kernel, dim3(128), dim3(256), 0, stream, w, wf);
    hipLaunchKernelGGL(linear_bf16_kernel, dim3(M_TOTAL / (2 * BM)), dim3(1024),
                       0, stream, x, wf, bias, out);
}